// Round 2
// baseline (305.355 us; speedup 1.0000x reference)
//
#include <hip/hip_runtime.h>

typedef float f32x4 __attribute__((ext_vector_type(4)));
typedef __bf16 bf16x8 __attribute__((ext_vector_type(8)));

constexpr float INV_SQRT_F = 0.17677669529663687f;  // 32^-0.5

__device__ __forceinline__ f32x4 mfma16(bf16x8 a, bf16x8 b) {
  const f32x4 z = {0.f, 0.f, 0.f, 0.f};
  return __builtin_amdgcn_mfma_f32_16x16x32_bf16(a, b, z, 0, 0, 0);
}

__device__ __forceinline__ bf16x8 load_frag8(const float* __restrict__ p) {
  f32x4 u = *reinterpret_cast<const f32x4*>(p);
  f32x4 v = *reinterpret_cast<const f32x4*>(p + 4);
  bf16x8 r;
  r[0] = (__bf16)u[0]; r[1] = (__bf16)u[1]; r[2] = (__bf16)u[2]; r[3] = (__bf16)u[3];
  r[4] = (__bf16)v[0]; r[5] = (__bf16)v[1]; r[6] = (__bf16)v[2]; r[7] = (__bf16)v[3];
  return r;
}

// One wave handles a 16-edge tile. MFMA 16x16x32 bf16:
//   A: lane holds row m=lane&15 (edge), k=(lane>>4)*8+j (feature in)
//   B: lane holds col n=lane&15 (feature out half), k=(lane>>4)*8+j  -> W[g][k]
//   D: lane holds col n=lane&15 (g), rows (lane>>4)*4+reg (edges)
__global__ __launch_bounds__(256, 2)
void leibniz_fused(const float* __restrict__ h0, const float* __restrict__ h1,
                   const float* __restrict__ h2, const float* __restrict__ g0,
                   const float* __restrict__ g1, const float* __restrict__ g2,
                   const float* __restrict__ Wg, const int* __restrict__ src,
                   float* __restrict__ out, int E)
{
  // W staged as bf16 fragments: [path][half][kchunk q][g_lo] of 8 bf16 (16B)
  __shared__ bf16x8 wlds[12 * 2 * 4 * 16];

  for (int c = threadIdx.x; c < 12 * 2 * 4 * 16; c += 256) {
    const int gl = c & 15;
    const int qq = (c >> 4) & 3;
    const int hf = (c >> 6) & 1;
    const int p  = c >> 7;
    const float* wp = Wg + (p * 32 + hf * 16 + gl) * 32 + qq * 8;
    bf16x8 f;
#pragma unroll
    for (int j = 0; j < 8; ++j) f[j] = (__bf16)(wp[j] * INV_SQRT_F);
    wlds[c] = f;
  }
  __syncthreads();

  const int lane = threadIdx.x & 63;
  const int wid  = threadIdx.x >> 6;
  const int m16  = lane & 15;   // A-row edge / B-col feature
  const int q    = lane >> 4;   // k-chunk selector; D-row group
  const int e0   = (blockIdx.x * 4 + wid) * 16;
  if (e0 >= E) return;

  const int node = src[e0 + m16];   // harness passes integer inputs as int32
  const int k0 = q * 8;

  // gathered A fragments (bf16) — loaded once, reused by all 12 paths
  const bf16x8 a0 = load_frag8(h0 + node * 32 + k0);
  bf16x8 a1[3];
#pragma unroll
  for (int s = 0; s < 3; ++s) a1[s] = load_frag8(h1 + node * 96 + s * 32 + k0);
  bf16x8 a2[9];
#pragma unroll
  for (int s = 0; s < 9; ++s) a2[s] = load_frag8(h2 + node * 288 + s * 32 + k0);

  const int er0 = e0 + q * 4;       // first of this lane's 4 output edges
  const int o1base = E * 32;
  const int o2base = E * 128;

#pragma unroll
  for (int half = 0; half < 2; ++half) {
    const int gc = m16 + 16 * half;  // output feature column
    const f32x4 z4 = {0.f, 0.f, 0.f, 0.f};
    f32x4 acc0 = z4;
    f32x4 acc1[3] = {z4, z4, z4};
    f32x4 acc2[9] = {z4, z4, z4, z4, z4, z4, z4, z4, z4};

#define WFRAG(P) (wlds[(((P) * 2 + half) * 4 + q) * 16 + m16])

    // ---- g0 phase: paths 0 (0,0->0 prod), 3 (1,0->1 prod), 4 (2,0->2 prod)
    {
      f32x4 g0v;
#pragma unroll
      for (int r = 0; r < 4; ++r) g0v[r] = g0[(er0 + r) * 32 + gc];
      {
        const bf16x8 wb = WFRAG(0);
        acc0 += mfma16(a0, wb) * g0v;
      }
      {
        const bf16x8 wb = WFRAG(3);
#pragma unroll
        for (int s = 0; s < 3; ++s) acc1[s] += mfma16(a1[s], wb) * g0v;
      }
      {
        const bf16x8 wb = WFRAG(4);
#pragma unroll
        for (int s = 0; s < 9; ++s) acc2[s] += mfma16(a2[s], wb) * g0v;
      }
    }

    // ---- g1 phase: paths 1 (prod), 5 (dot), 6 (cross), 7 (outer), 8 (mat_vec)
    {
      f32x4 g1v[3];
#pragma unroll
      for (int s = 0; s < 3; ++s)
#pragma unroll
        for (int r = 0; r < 4; ++r)
          g1v[s][r] = g1[((er0 + r) * 3 + s) * 32 + gc];
      {
        const bf16x8 wb = WFRAG(1);
        const f32x4 t = mfma16(a0, wb);
#pragma unroll
        for (int s = 0; s < 3; ++s) acc1[s] += t * g1v[s];
      }
      {
        const bf16x8 wb = WFRAG(5);
#pragma unroll
        for (int s = 0; s < 3; ++s) acc0 += mfma16(a1[s], wb) * g1v[s];
      }
      {
        const bf16x8 wb = WFRAG(6);
        const f32x4 c0 = mfma16(a1[0], wb);
        const f32x4 c1 = mfma16(a1[1], wb);
        const f32x4 c2 = mfma16(a1[2], wb);
        acc1[0] += c1 * g1v[2] - c2 * g1v[1];
        acc1[1] += c2 * g1v[0] - c0 * g1v[2];
        acc1[2] += c0 * g1v[1] - c1 * g1v[0];
      }
      {
        const bf16x8 wb = WFRAG(7);
        const f32x4 o0 = mfma16(a1[0], wb);
        const f32x4 o1 = mfma16(a1[1], wb);
        const f32x4 o2 = mfma16(a1[2], wb);
        const f32x4 tr3 = (o0 * g1v[0] + o1 * g1v[1] + o2 * g1v[2]) * (1.f / 3.f);
        acc2[0] += o0 * g1v[0] - tr3;
        acc2[1] += o0 * g1v[1];
        acc2[2] += o0 * g1v[2];
        acc2[3] += o1 * g1v[0];
        acc2[4] += o1 * g1v[1] - tr3;
        acc2[5] += o1 * g1v[2];
        acc2[6] += o2 * g1v[0];
        acc2[7] += o2 * g1v[1];
        acc2[8] += o2 * g1v[2] - tr3;
      }
      {
        const bf16x8 wb = WFRAG(8);
#pragma unroll
        for (int i = 0; i < 3; ++i)
#pragma unroll
          for (int j = 0; j < 3; ++j)
            acc1[i] += mfma16(a2[i * 3 + j], wb) * g1v[j];
      }
    }

    // ---- g2 phase: paths 2 (prod), 9 (vec_mat), 10 (double_dot), 11 (mat_mul_sym)
    {
      f32x4 g2v[9];
#pragma unroll
      for (int s = 0; s < 9; ++s)
#pragma unroll
        for (int r = 0; r < 4; ++r)
          g2v[s][r] = g2[((er0 + r) * 9 + s) * 32 + gc];
      {
        const bf16x8 wb = WFRAG(2);
        const f32x4 t = mfma16(a0, wb);
#pragma unroll
        for (int s = 0; s < 9; ++s) acc2[s] += t * g2v[s];
      }
      {
        const bf16x8 wb = WFRAG(9);
        const f32x4 v0 = mfma16(a1[0], wb);
        const f32x4 v1 = mfma16(a1[1], wb);
        const f32x4 v2 = mfma16(a1[2], wb);
#pragma unroll
        for (int j = 0; j < 3; ++j)
          acc1[j] += v0 * g2v[0 * 3 + j] + v1 * g2v[1 * 3 + j] + v2 * g2v[2 * 3 + j];
      }
      {
        const bf16x8 wb = WFRAG(10);
#pragma unroll
        for (int s = 0; s < 9; ++s) acc0 += mfma16(a2[s], wb) * g2v[s];
      }
      {
        // raw_ij = sum_k ht[i][k] g2[k][j]; out2 += 0.5(raw+raw^T) - (tr/3) I
        const bf16x8 wb = WFRAG(11);
#pragma unroll
        for (int k = 0; k < 3; ++k) {
          const f32x4 m0 = mfma16(a2[0 * 3 + k], wb);
          const f32x4 m1 = mfma16(a2[1 * 3 + k], wb);
          const f32x4 m2 = mfma16(a2[2 * 3 + k], wb);
          const f32x4 gk0 = g2v[k * 3 + 0];
          const f32x4 gk1 = g2v[k * 3 + 1];
          const f32x4 gk2 = g2v[k * 3 + 2];
          const f32x4 tk3 = (m0 * gk0 + m1 * gk1 + m2 * gk2) * (1.f / 3.f);
          acc2[0] += m0 * gk0 - tk3;
          acc2[4] += m1 * gk1 - tk3;
          acc2[8] += m2 * gk2 - tk3;
          const f32x4 s01 = (m0 * gk1 + m1 * gk0) * 0.5f;
          acc2[1] += s01; acc2[3] += s01;
          const f32x4 s02 = (m0 * gk2 + m2 * gk0) * 0.5f;
          acc2[2] += s02; acc2[6] += s02;
          const f32x4 s12 = (m1 * gk2 + m2 * gk1) * 0.5f;
          acc2[5] += s12; acc2[7] += s12;
        }
      }
    }

    // ---- stores
#pragma unroll
    for (int r = 0; r < 4; ++r) out[(er0 + r) * 32 + gc] = acc0[r];
#pragma unroll
    for (int s = 0; s < 3; ++s)
#pragma unroll
      for (int r = 0; r < 4; ++r)
        out[o1base + ((er0 + r) * 3 + s) * 32 + gc] = acc1[s][r];
#pragma unroll
    for (int s = 0; s < 9; ++s)
#pragma unroll
      for (int r = 0; r < 4; ++r)
        out[o2base + ((er0 + r) * 9 + s) * 32 + gc] = acc2[s][r];
#undef WFRAG
  }
}

extern "C" void kernel_launch(void* const* d_in, const int* in_sizes, int n_in,
                              void* d_out, int out_size, void* d_ws, size_t ws_size,
                              hipStream_t stream) {
  const float* h0 = (const float*)d_in[0];
  const float* h1 = (const float*)d_in[1];
  const float* h2 = (const float*)d_in[2];
  const float* g0 = (const float*)d_in[3];
  const float* g1 = (const float*)d_in[4];
  const float* g2 = (const float*)d_in[5];
  const float* Wg = (const float*)d_in[6];
  const int* src = (const int*)d_in[7];  // harness passes integer inputs as int32
  const int E = in_sizes[7];
  const int blocks = E / 64;  // 4 waves/block * 16 edges/wave
  leibniz_fused<<<blocks, 256, 0, stream>>>(h0, h1, h2, g0, g1, g2, Wg, src,
                                            (float*)d_out, E);
}